// Round 1
// 168.239 us; speedup vs baseline: 1.0028x; 1.0028x over previous
//
#include <hip/hip_runtime.h>
#include <hip/hip_bf16.h>
#include <stdint.h>

typedef short v8s __attribute__((ext_vector_type(8)));
typedef float v4f __attribute__((ext_vector_type(4)));
typedef float v16f __attribute__((ext_vector_type(16)));

#define N_EMBD 1024
#define HEAD 128
#define TOKENS 16384   // 8*2048
#define T_SEQ 2048
#define BATCH 8
#define BPB 96         // attn blocks/batch: sum_{qt2=0}^{15} ceil((2qt2+2)/3)

__device__ __forceinline__ short f2bf(float f) {
    union { float f; uint32_t u; } c; c.f = f;
    uint32_t u = c.u;
    uint32_t r = (u + 0x7fffu + ((u >> 16) & 1u)) >> 16;
    return (short)r;
}

__device__ __forceinline__ float bf2f(short s) {
    union { uint32_t u; float f; } c; c.u = ((uint32_t)(uint16_t)s) << 16;
    return c.f;
}

// ---------------- kernel 1: W transpose + bf16 convert ----------------
__global__ __launch_bounds__(256)
void wt_kernel(const float* __restrict__ Wq, const float* __restrict__ Wk,
               const float* __restrict__ Wv, short* __restrict__ wt) {
    int tid = blockIdx.x * 256 + threadIdx.x;
    int w   = tid >> 17;
    int rem = tid & 131071;                          // c*128 + h
    int c = rem >> 7, h = rem & 127;
    const float* src = (w == 0) ? Wq : ((w == 1) ? Wk : Wv);
    wt[w * 131072 + h * 1024 + c] = f2bf(src[rem]);
}

// ---------------- kernel 2: QKV GEMM, depth-2 reg prefetch, 32x32x16 ----------------
// BM=64, BN=128, BK=32. 768 blocks, XCD-grouped: bid=(mt_local*3+w)*8+xcd,
// mt = xcd*32+mt_local -> the 3 w-siblings of an x tile are co-resident on one XCD.
// DEPTH-2 register prefetch: iter `it` issues loads for it+2; the stage-write for
// it+1 consumes registers loaded one FULL iteration earlier (~1000 cyc slack vs
// ~150 cyc in the depth-1 version). Register loads survive s_barrier (no vmcnt
// drain for VGPR-destination loads). 1 barrier/iter, loop unrolled x2 so the
// register-set index is compile-time (no scratch spill).
__global__ __launch_bounds__(256)
void qkv_gemm(const float* __restrict__ x, const short* __restrict__ wt,
              short* __restrict__ qkv, short* __restrict__ vT) {
    const int bid = blockIdx.x;
    const int xcd = bid & 7, q = bid >> 3;
    const int mt  = xcd * 32 + q / 3;
    const int w   = q % 3;
    const int m0  = mt * 64;

    __shared__ short smem[2][64 * 40 + 128 * 40];   // dbuf: sA 64x40 | sB 128x40

    const int t = threadIdx.x;
    const int lane = t & 63, wv = t >> 6;
    const int l31 = lane & 31, l1 = lane >> 5;
    const int wm = wv & 1, wn = wv >> 1;

    const short* wtw = wt + w * 131072;

    // staging coords: A chunks (float4): rows arow, arow+32; B chunks (16B): rows brow, brow+64
    const int arow = t >> 3, ac4 = t & 7;
    const int brow = t >> 2, bc8 = t & 3;
    const float* aptr0 = x + (size_t)(m0 + arow) * 1024 + ac4 * 4;
    const float* aptr1 = x + (size_t)(m0 + arow + 32) * 1024 + ac4 * 4;
    const short* bptr0 = wtw + brow * 1024 + bc8 * 8;
    const short* bptr1 = wtw + (brow + 64) * 1024 + bc8 * 8;

    // prologue: issue iter-0 (set0) and iter-1 (set1) loads
    float4 a00 = *(const float4*)(aptr0);
    float4 a01 = *(const float4*)(aptr1);
    uint4  b00 = *(const uint4*)(bptr0);
    uint4  b01 = *(const uint4*)(bptr1);
    float4 a10 = *(const float4*)(aptr0 + 32);
    float4 a11 = *(const float4*)(aptr1 + 32);
    uint4  b10 = *(const uint4*)(bptr0 + 32);
    uint4  b11 = *(const uint4*)(bptr1 + 32);

    v16f acc[2];
    for (int i = 0; i < 16; ++i) { acc[0][i] = 0.f; acc[1][i] = 0.f; }

#define STAGE(BUF, A0, A1, B0, B1) do {                                          \
        short* sA_ = smem[BUF]; short* sB_ = smem[BUF] + 64 * 40;                \
        union { short s[4]; uint64_t u; } p0_, p1_;                              \
        p0_.s[0] = f2bf((A0).x); p0_.s[1] = f2bf((A0).y);                        \
        p0_.s[2] = f2bf((A0).z); p0_.s[3] = f2bf((A0).w);                        \
        p1_.s[0] = f2bf((A1).x); p1_.s[1] = f2bf((A1).y);                        \
        p1_.s[2] = f2bf((A1).z); p1_.s[3] = f2bf((A1).w);                        \
        *(uint64_t*)(&sA_[arow * 40 + ac4 * 4]) = p0_.u;                         \
        *(uint64_t*)(&sA_[(arow + 32) * 40 + ac4 * 4]) = p1_.u;                  \
        *(uint4*)(&sB_[brow * 40 + bc8 * 8]) = (B0);                             \
        *(uint4*)(&sB_[(brow + 64) * 40 + bc8 * 8]) = (B1);                      \
    } while (0)

#define COMPUTE(BUF) do {                                                        \
        const short* sA_ = smem[BUF];                                            \
        const short* sB_ = smem[BUF] + 64 * 40;                                  \
        for (int ks = 0; ks < 2; ++ks) {                                         \
            v8s a_ = *(const v8s*)&sA_[(wm * 32 + l31) * 40 + ks * 16 + l1 * 8]; \
            v8s b0_ = *(const v8s*)&sB_[(wn * 64 + l31) * 40 + ks * 16 + l1 * 8];\
            acc[0] = __builtin_amdgcn_mfma_f32_32x32x16_bf16(a_, b0_, acc[0], 0, 0, 0); \
            v8s b1_ = *(const v8s*)&sB_[(wn * 64 + 32 + l31) * 40 + ks * 16 + l1 * 8]; \
            acc[1] = __builtin_amdgcn_mfma_f32_32x32x16_bf16(a_, b1_, acc[1], 0, 0, 0); \
        }                                                                        \
    } while (0)

    // iter-0 stage into buf0 (waits only set0's loads; set1 stays in flight)
    STAGE(0, a00, a01, b00, b01);

    for (int it = 0; it < 32; it += 2) {
        // even iter `it`: set0 was staged last iter -> free; issue loads for it+2
        if (it + 2 < 32) {
            int kk = (it + 2) * 32;
            a00 = *(const float4*)(aptr0 + kk);
            a01 = *(const float4*)(aptr1 + kk);
            b00 = *(const uint4*)(bptr0 + kk);
            b01 = *(const uint4*)(bptr1 + kk);
        }
        __syncthreads();                 // buf0 (chunk it) visible
        COMPUTE(0);
        STAGE(1, a10, a11, b10, b11);    // chunk it+1, loaded a full iter ago
        // odd iter it+1: set1 now free; issue loads for it+3
        if (it + 3 < 32) {
            int kk = (it + 3) * 32;
            a10 = *(const float4*)(aptr0 + kk);
            a11 = *(const float4*)(aptr1 + kk);
            b10 = *(const uint4*)(bptr0 + kk);
            b11 = *(const uint4*)(bptr1 + kk);
        }
        __syncthreads();                 // buf1 (chunk it+1) visible
        COMPUTE(1);
        if (it + 2 < 32) STAGE(0, a00, a01, b00, b01);   // chunk it+2
    }

#undef STAGE
#undef COMPUTE

    // epilogue. 32x32 C-layout: col = lane&31, row m = (reg&3) + 8*(reg>>2) + 4*l1
    if (w < 2) {
        short* outw = qkv + (size_t)w * TOKENS * HEAD;
        for (int ni = 0; ni < 2; ++ni) {
            int col = wn * 64 + ni * 32 + l31;
            for (int reg = 0; reg < 16; ++reg) {
                int m = (reg & 3) + 8 * (reg >> 2) + 4 * l1;
                outw[(size_t)(m0 + wm * 32 + m) * HEAD + col] = f2bf(acc[ni][reg]);
            }
        }
    } else {
        __syncthreads();
        short* sT = (short*)smem;   // [128 d][stride 72] tokens 0..63
        for (int ni = 0; ni < 2; ++ni) {
            int col = wn * 64 + ni * 32 + l31;
            for (int g = 0; g < 4; ++g) {
                union { short s[4]; uint64_t u; } pk;
                for (int r = 0; r < 4; ++r) pk.s[r] = f2bf(acc[ni][g * 4 + r]);
                *(uint64_t*)(&sT[col * 72 + wm * 32 + 8 * g + 4 * l1]) = pk.u;
            }
        }
        __syncthreads();
        for (int it = 0; it < 4; ++it) {
            int c = it * 256 + t;
            int col = c >> 3, c8 = c & 7;
            uint4 d = *(const uint4*)(&sT[col * 72 + c8 * 8]);
            *(uint4*)(&vT[(size_t)col * TOKENS + m0 + c8 * 8]) = d;
        }
    }
}

// ---------------- kernel 3: flash attention, S^T operand-swap ----------------
// S^T = K·Q^T (A=K, B=Q) -> lane holds qrow=ln, keys=qd*4+r: P written as b64.
// O^T = V^T·P^T-ish via mfma(vf, pf): lane holds qrow=ln, d=oni*16+qd*4+r.
__global__ __launch_bounds__(256)
void attn_kernel(const short* __restrict__ qb, const short* __restrict__ kb,
                 const short* __restrict__ vT, short* __restrict__ po,
                 float* __restrict__ pl) {
    const int bid = blockIdx.x;
    const int b  = bid & 7;
    const int r0 = bid >> 3;        // 0..95
    int qt2 = 0, c0 = 0;
    for (;;) { int sz = (2 * qt2 + 4) / 3; if (r0 < c0 + sz) break; c0 += sz; ++qt2; }
    const int s = r0 - c0;
    const int q0 = qt2 * 128;
    const int nkt = 2 * qt2 + 2;
    const int kt0 = s * 3;
    const int kt1 = (kt0 + 3 < nkt) ? (kt0 + 3) : nkt;

    __shared__ short sK[64 * 128];    // swizzled 16B chunks
    __shared__ short sV[128 * 64];    // V^T [d][key], swizzled
    __shared__ short sP[128 * 72];    // P [qrow][key], stride 72

    const int t = threadIdx.x;
    const int wv = t >> 6, lane = t & 63, ln = lane & 15, qd = lane >> 4;
    const int wrow0 = q0 + wv * 32;

    v8s qf[2][4];
    for (int qg = 0; qg < 2; ++qg) {
        const short* qrow = qb + ((size_t)(b * T_SEQ + wrow0 + qg * 16 + ln)) * HEAD;
        for (int ks = 0; ks < 4; ++ks)
            qf[qg][ks] = *(const v8s*)(qrow + ks * 32 + qd * 8);
    }

    v4f o[2][8] = {};
    float rs[2] = {0.f, 0.f};
    const float sc = 1.4426950408889634f / 11.313708498984761f;  // log2e / sqrt(128)

    for (int kt = kt0; kt < kt1; ++kt) {
        __syncthreads();
        const short* kbase = kb + ((size_t)(b * T_SEQ + kt * 64)) * HEAD;
        for (int it = 0; it < 4; ++it) {
            int c = it * 256 + t;
            int row = c >> 4, ch = c & 15;
            uint4 d = *(const uint4*)(kbase + row * HEAD + ch * 8);
            int sch = (ch & 8) | ((ch ^ row) & 7);
            *(uint4*)(&sK[row * 128 + sch * 8]) = d;
        }
        const short* vbase = vT + (size_t)(b * T_SEQ + kt * 64);
        for (int it = 0; it < 4; ++it) {
            int c = it * 256 + t;
            int dd = c >> 3, ch = c & 7;
            uint4 d = *(const uint4*)(vbase + (size_t)dd * TOKENS + ch * 8);
            *(uint4*)(&sV[dd * 64 + ((ch ^ dd) & 7) * 8]) = d;
        }
        __syncthreads();

        if (kt * 64 >= wrow0 + 32) continue;   // wave fully masked

        // S^T: A = K fragments, B = Q fragments
        v4f st[2][4] = {};
        for (int ni = 0; ni < 4; ++ni) {
            int krow = ni * 16 + ln;
            for (int ks = 0; ks < 4; ++ks) {
                int ch = ks * 4 + qd;
                v8s kf = *(const v8s*)&sK[krow * 128 + ((ch & 8) | ((ch ^ krow) & 7)) * 8];
                st[0][ni] = __builtin_amdgcn_mfma_f32_16x16x32_bf16(kf, qf[0][ks], st[0][ni], 0, 0, 0);
                st[1][ni] = __builtin_amdgcn_mfma_f32_16x16x32_bf16(kf, qf[1][ks], st[1][ni], 0, 0, 0);
            }
        }

        // softmax: lane holds qrow=ln, key = ni*16 + qd*4 + r -> b64 P writes
        const bool needMask = (kt * 64 + 63 > wrow0);
        for (int qg = 0; qg < 2; ++qg) {
            int prow = wv * 32 + qg * 16 + ln;
            int qrow_g = wrow0 + qg * 16 + ln;
            for (int ni = 0; ni < 4; ++ni) {
                union { short s[4]; uint64_t u; } pk;
                for (int r = 0; r < 4; ++r) {
                    float p = exp2f(st[qg][ni][r] * sc);
                    int kg = kt * 64 + ni * 16 + qd * 4 + r;
                    if (needMask && kg > qrow_g) p = 0.f;
                    rs[qg] += p;
                    pk.s[r] = f2bf(p);
                }
                *(uint64_t*)(&sP[prow * 72 + ni * 16 + qd * 4]) = pk.u;
            }
        }

        // O^T += : A = V fragments, B = P fragments (same-wave sP rows, in-order)
        for (int kk2 = 0; kk2 < 2; ++kk2) {
            v8s pf0 = *(const v8s*)&sP[(wv * 32 + ln) * 72 + kk2 * 32 + qd * 8];
            v8s pf1 = *(const v8s*)&sP[(wv * 32 + 16 + ln) * 72 + kk2 * 32 + qd * 8];
            for (int oni = 0; oni < 8; ++oni) {
                int dd = oni * 16 + ln;
                int ch = kk2 * 4 + qd;
                v8s vf = *(const v8s*)&sV[dd * 64 + ((ch ^ dd) & 7) * 8];
                o[0][oni] = __builtin_amdgcn_mfma_f32_16x16x32_bf16(vf, pf0, o[0][oni], 0, 0, 0);
                o[1][oni] = __builtin_amdgcn_mfma_f32_16x16x32_bf16(vf, pf1, o[1][oni], 0, 0, 0);
            }
        }
    }

    // row sums: reduce across qd lanes (xor 16, 32)
    float lsum[2];
    for (int qg = 0; qg < 2; ++qg) {
        float v = rs[qg];
        v += __shfl_xor(v, 16);
        v += __shfl_xor(v, 32);
        lsum[qg] = v;
    }

    short* pob = po + (size_t)bid * 128 * 128;
    for (int qg = 0; qg < 2; ++qg)
        for (int oni = 0; oni < 8; ++oni) {
            union { short s[4]; uint2 u; } pk;
            for (int r = 0; r < 4; ++r) pk.s[r] = f2bf(o[qg][oni][r]);
            *(uint2*)(&pob[(((qg * 8 + oni) * 4 + wv) * 64 + lane) * 4]) = pk.u;
        }
    if (lane < 16)
        for (int qg = 0; qg < 2; ++qg)
            pl[bid * 128 + wv * 32 + qg * 16 + lane] = lsum[qg];
}

// ---------------- kernel 4: combine splits ----------------
__global__ __launch_bounds__(256)
void combine_kernel(const short* __restrict__ po, const float* __restrict__ pl,
                    float* __restrict__ out) {
    const int bid = blockIdx.x;          // 512: b<<6 | qt2<<2 | qh<<1 | dh
    const int dh  = bid & 1;
    const int qh  = (bid >> 1) & 1;
    const int qt2 = (bid >> 2) & 15;
    const int b   = bid >> 6;
    int cum = 0;
    for (int j = 0; j < qt2; ++j) cum += (2 * j + 4) / 3;
    const int S = (2 * qt2 + 4) / 3;

    const int t = threadIdx.x;
    const int wv = t >> 6, lane = t & 63, ln = lane & 15, qd = lane >> 4;

    float l = 0.f;
    float accv[4][4] = {};

    for (int si = 0; si < S; ++si) {
        int slot = (cum + si) * 8 + b;
        l += pl[slot * 128 + wv * 32 + qh * 16 + ln];
        const short* pob = po + (size_t)slot * 16384;
        for (int oi = 0; oi < 4; ++oi) {
            int oni = dh * 4 + oi;
            union { short s[4]; uint2 u; } pk;
            pk.u = *(const uint2*)(&pob[(((qh * 8 + oni) * 4 + wv) * 64 + lane) * 4]);
            for (int r = 0; r < 4; ++r) accv[oi][r] += bf2f(pk.s[r]);
        }
    }
    float inv = 1.f / l;
    // lane holds qrow = ln, d = (dh*4+oi)*16 + qd*4 + r
    float* ob = out + ((size_t)(b * T_SEQ) + qt2 * 128 + wv * 32 + qh * 16 + ln) * HEAD;
    for (int oi = 0; oi < 4; ++oi) {
        float4 o4 = make_float4(accv[oi][0] * inv, accv[oi][1] * inv,
                                accv[oi][2] * inv, accv[oi][3] * inv);
        *(float4*)(ob + (dh * 4 + oi) * 16 + qd * 4) = o4;
    }
}

extern "C" void kernel_launch(void* const* d_in, const int* in_sizes, int n_in,
                              void* d_out, int out_size, void* d_ws, size_t ws_size,
                              hipStream_t stream) {
    const float* x  = (const float*)d_in[0];
    const float* Wk = (const float*)d_in[1];
    const float* Wq = (const float*)d_in[2];
    const float* Wv = (const float*)d_in[3];
    float* out = (float*)d_out;

    char* ws = (char*)d_ws;
    short* wt = (short*)ws;                               // 768 KB
    short* qb = (short*)(ws + 0x100000u);                 // 4 MB
    short* kb = (short*)(ws + 0x500000u);                 // 4 MB
    short* vT = (short*)(ws + 0x900000u);                 // 4 MB, [128][16384]
    short* po = (short*)(ws + 0xD00000u);                 // 768*32KB = 24 MB
    float* pl = (float*)(ws + 0x2500000u);                // 768*128 f32
    short* qkv = qb;

    wt_kernel<<<1536, 256, 0, stream>>>(Wq, Wk, Wv, wt);
    qkv_gemm<<<768, 256, 0, stream>>>(x, wt, qkv, vT);
    attn_kernel<<<BATCH * BPB, 256, 0, stream>>>(qb, kb, vT, po, pl);
    combine_kernel<<<512, 256, 0, stream>>>(po, pl, out);
}